// Round 4
// baseline (487.137 us; speedup 1.0000x reference)
//
#include <hip/hip_runtime.h>

// CompressionLayer: B=256, H=W=512, 16x16 chunks -> N=1024, KIN=256, KOUT=64.
// R4 = R3 with three fixes (R3 failed correctness, absmax 3.125):
//  1. W fragment base was missing the ci*32 chunk offset (wrong weights for
//     all ci != 0) -- the dominant error source.
//  2. bias base was likewise missing ci*2048.
//  3. restore sched_barrier(0) pins around stage_issue(s+2): stage s+2 writes
//     the SAME LDS buffer stage s reads (depth-2 dbuf); pinning the DMA after
//     the lgkmcnt-forcing conversions is what made R2 race-free.
// Theory under test (unchanged from R3): prior versions' vmem shattered into
// 16-64B segments on 64 lines; per-line miss tracking caps in-flight bytes ->
// ~2 TB/s. Full-line lane-ordered requests should unlock HBM BW.
//  - Kernel A: Wk fp32 -> bf16 in fragment-linear layout (W reads become
//    contiguous 1KB runs; W bytes halved; no W-convert in hot loop).
//  - Kernel B: blocks own cj-PAIRS so x rows are full 128B lines, DMA'd via
//    global_load_lds (linear LDS dest, 32B-granule source swizzle for
//    conflict-free ds_read_b128). W frags in registers from L1/L2.

typedef __bf16 bf16x8 __attribute__((ext_vector_type(8)));  // MFMA A/B operand
typedef float  f32x4  __attribute__((ext_vector_type(4)));  // MFMA C/D

union bfpack { unsigned short s[8]; bf16x8 v; };

__device__ __forceinline__ unsigned short f2bf(float f) {
  union { float f; unsigned u; } v; v.f = f;
  unsigned r = v.u + 0x7fffu + ((v.u >> 16) & 1u);   // RNE (inputs finite)
  return (unsigned short)(r >> 16);
}

typedef __attribute__((address_space(1))) const void GV;
typedef __attribute__((address_space(3))) void LV;

// ---------------- Kernel A: W fp32 -> bf16, fragment-linear ----------------
// Wc layout (ushort elems): [n][ks 0..7][nt 0..3][lane 0..63][j 0..7]
// content: W[n][o = nt*16 + (lane&15)][k = ks*32 + (lane>>4)*8 + j]
// Reads fully coalesced (1KB runs); writes are 8B scattered (posted, L2-merged).
__global__ __launch_bounds__(256) void wconv_kernel(
    const float* __restrict__ Wk, unsigned short* __restrict__ Wc) {
  const int n = blockIdx.x, t = threadIdx.x;
  const float4* src = (const float4*)(Wk + (size_t)n * 16384);
  unsigned short* dst = Wc + (size_t)n * 16384;
  #pragma unroll
  for (int it = 0; it < 16; ++it) {
    const int idx = it * 256 + t;              // float4 index within [64 o][64 kq]
    float4 g = src[idx];
    const int o = idx >> 6, kq = idx & 63;     // k = kq*4 + e
    const int ks = kq >> 3, quad = (kq >> 1) & 3, h = kq & 1;
    ushort4 p;
    p.x = f2bf(g.x); p.y = f2bf(g.y); p.z = f2bf(g.z); p.w = f2bf(g.w);
    *(ushort4*)&dst[(size_t)((ks * 4 + (o >> 4)) * 64 + (quad * 16 + (o & 15))) * 8 + h * 4] = p;
  }
}

// ---------------- Kernel B: main compute ----------------
// 512 blocks = (ci 0..31) x (cjp 0..15, a cj-PAIR); 512 threads = 8 waves.
// Each wave: 32 batches (2 groups of 16). x staged per (group,ks): 16 b x
// 2 rows x 128B = 4KB, wave-private double buffer, 2-deep DMA pipeline.
__global__ __launch_bounds__(512, 4) void comp_kernel(
    const float* __restrict__ x, const unsigned short* __restrict__ Wc,
    const float* __restrict__ bk, float* __restrict__ out) {
  __shared__ float bs[128];
  __shared__ __align__(16) char Xs[8][2][4096];   // 64KB; total 66KB -> 2 blk/CU

  const int bid = blockIdx.x;
  // XCD swizzle: bid%8 -> XCD (round-robin dispatch); same-XCD bids get
  // consecutive work ids => adjacent cjp share out lines within one L2.
  const int w = ((bid & 7) << 6) | (bid >> 3);    // bijective for 512 = 8*64
  const int ci = w >> 4, cjp = w & 15;
  const int t = threadIdx.x;
  const int wave = t >> 6, lane = t & 63;
  const int m15 = lane & 15, quad = lane >> 4;

  // chunk-pair base index n0 = ci*32 + cjp*2  (R4 fix: ci term!)
  const int n0 = ci * 32 + cjp * 2;

  if (t < 32) *(float4*)&bs[t * 4] = *(const float4*)&bk[(size_t)n0 * 64 + t * 4];
  __syncthreads();   // bias ready; the only barrier

  const char* xb = (const char*)x + (size_t)ci * 32768 + (size_t)cjp * 128;
  const int sgm = lane >> 3, g = lane & 7;        // line-segment, granule-in-line
  const int b_sub = sgm >> 1, r_dma = sgm & 1;

  // LDS read-side constants. Slab(b,r) = (b>>2)*1024 + (b&3)*256 + r*128.
  // 32B-granule-pair p in a line holds true pair (p ^ (b&3)) -> 2-way bank
  // alias only (free, m136).
  const int slab = ((m15 >> 2) << 10) | ((m15 & 3) << 8) | ((quad >> 1) << 7);
  const int sw = m15 & 3;
  const int c2_0 = (quad & 1) ^ sw;               // ch 0 true pair = (quad&1)
  const int c2_1 = (2 | (quad & 1)) ^ sw;         // ch 1 true pair = 2|(quad&1)

  // W fragment base: this lane's 16B within the [ks][nt] 1KB slab (lane-linear).
  const unsigned short* wp0 = Wc + (size_t)n0 * 16384 + lane * 8;

  // DMA one 4KB stage s = grp*8 + ks: 16 batches x rows {2ks,2ks+1}, full lines.
  auto stage_issue = [&](int s) {
    const int grp = s >> 3, ks = s & 7;
    char* dstb = &Xs[wave][s & 1][0];
    #pragma unroll
    for (int i = 0; i < 4; ++i) {
      const int bl = i * 4 + b_sub;                               // 0..15
      const int b  = wave * 32 + grp * 16 + bl;
      const int col = (((g >> 1) ^ (bl & 3)) << 5) | ((g & 1) << 4);  // swz 32B pairs
      const char* src = xb + (size_t)b * 1048576 + (2 * ks + r_dma) * 2048 + col;
      __builtin_amdgcn_global_load_lds((GV*)src, (LV*)(dstb + i * 1024), 16, 0, 0);
    }
  };

  stage_issue(0);
  stage_issue(1);

  #pragma unroll
  for (int grp = 0; grp < 2; ++grp) {
    f32x4 acc[2][4] = {{{0,0,0,0},{0,0,0,0},{0,0,0,0},{0,0,0,0}},
                       {{0,0,0,0},{0,0,0,0},{0,0,0,0},{0,0,0,0}}};
    #pragma unroll
    for (int ks = 0; ks < 8; ++ks) {
      const int s = grp * 8 + ks;
      // Counted wait for stage s's DMA. FIFO: at s==8 the group-0 epilogue
      // stores (8) + DMA(9) (4) may remain -> 12; otherwise DMA(s+1) -> 4.
      if (s == 8) asm volatile("s_waitcnt vmcnt(12)" ::: "memory");
      else        asm volatile("s_waitcnt vmcnt(4)"  ::: "memory");
      __builtin_amdgcn_sched_barrier(0);

      // W frags: 8 x 16B lane-linear loads (1KB runs; L1/L2-hot after wave 0).
      bf16x8 bw[2][4];
      #pragma unroll
      for (int ch = 0; ch < 2; ++ch)
        #pragma unroll
        for (int nt = 0; nt < 4; ++nt)
          bw[ch][nt] = *(const bf16x8*)(wp0 + (size_t)ch * 16384 + ks * 2048 + nt * 512);

      // A frags: 8 consecutive k-floats per chunk from the swizzled stage.
      const char* Xb = &Xs[wave][s & 1][0];
      float4 u0 = *(const float4*)(Xb + slab + c2_0 * 32);
      float4 u1 = *(const float4*)(Xb + slab + c2_0 * 32 + 16);
      float4 u2 = *(const float4*)(Xb + slab + c2_1 * 32);
      float4 u3 = *(const float4*)(Xb + slab + c2_1 * 32 + 16);
      bfpack a0, a1;
      a0.s[0] = f2bf(u0.x); a0.s[1] = f2bf(u0.y); a0.s[2] = f2bf(u0.z); a0.s[3] = f2bf(u0.w);
      a0.s[4] = f2bf(u1.x); a0.s[5] = f2bf(u1.y); a0.s[6] = f2bf(u1.z); a0.s[7] = f2bf(u1.w);
      a1.s[0] = f2bf(u2.x); a1.s[1] = f2bf(u2.y); a1.s[2] = f2bf(u2.z); a1.s[3] = f2bf(u2.w);
      a1.s[4] = f2bf(u3.x); a1.s[5] = f2bf(u3.y); a1.s[6] = f2bf(u3.z); a1.s[7] = f2bf(u3.w);

      // Next-next stage DMA. R4 fix: pin with sched_barrier(0) on BOTH sides.
      // The conversions above force lgkmcnt drain of this stage's ds_reads;
      // pinning the DMA after them guarantees it cannot overwrite buffer
      // (s&1) (stage s+2 shares it) before the reads complete. (R2-proven.)
      if (s + 2 < 16) {
        __builtin_amdgcn_sched_barrier(0);
        stage_issue(s + 2);
        __builtin_amdgcn_sched_barrier(0);
      }

      // Swapped operands: A=W (rows=o), B=x (cols=batch) -> D[o][batch].
      #pragma unroll
      for (int nt = 0; nt < 4; ++nt) {
        acc[0][nt] = __builtin_amdgcn_mfma_f32_16x16x32_bf16(bw[0][nt], a0.v, acc[0][nt], 0, 0, 0);
        acc[1][nt] = __builtin_amdgcn_mfma_f32_16x16x32_bf16(bw[1][nt], a1.v, acc[1][nt], 0, 0, 0);
      }
    }

    // Epilogue: D row(o) = nt*16 + quad*4 + r, col(b) = m15. float4 stores.
    const int b = wave * 32 + grp * 16 + m15;
    float* op = out + (size_t)b * 65536 + (size_t)(ci * 8) * 256 + cjp * 16;
    #pragma unroll
    for (int ch = 0; ch < 2; ++ch)
      #pragma unroll
      for (int nt = 0; nt < 4; ++nt) {
        const int o0 = nt * 16 + quad * 4;           // o0..o0+3, one oh row
        float4 b4 = *(const float4*)&bs[ch * 64 + o0];
        float4 res;
        res.x = fmaxf(acc[ch][nt][0] + b4.x, 0.f);
        res.y = fmaxf(acc[ch][nt][1] + b4.y, 0.f);
        res.z = fmaxf(acc[ch][nt][2] + b4.z, 0.f);
        res.w = fmaxf(acc[ch][nt][3] + b4.w, 0.f);
        *(float4*)&op[(o0 >> 3) * 256 + ch * 8 + (o0 & 7)] = res;
      }
  }
}

extern "C" void kernel_launch(void* const* d_in, const int* in_sizes, int n_in,
                              void* d_out, int out_size, void* d_ws, size_t ws_size,
                              hipStream_t stream) {
  const float* x  = (const float*)d_in[0];
  const float* Wk = (const float*)d_in[1];
  const float* bk = (const float*)d_in[2];
  float* out = (float*)d_out;
  unsigned short* Wc = (unsigned short*)d_ws;       // 32 MiB of workspace
  wconv_kernel<<<dim3(1024), dim3(256), 0, stream>>>(Wk, Wc);
  comp_kernel<<<dim3(512), dim3(512), 0, stream>>>(x, Wc, bk, out);
}

// Round 5
// 444.157 us; speedup vs baseline: 1.0968x; 1.0968x over previous
//
#include <hip/hip_runtime.h>

// CompressionLayer: B=256, H=W=512, 16x16 chunks -> N=1024, KIN=256, KOUT=64.
// R5 theory: DRAM row locality. All prior versions read x in 128-256B touches
// strided 1 MiB apart -> row-miss-dominated HBM at ~1/3 efficiency (~2.5 TB/s
// across R0-R4 regardless of pipelining). Fix: block = (ci, 16-batch slice)
// owns ALL 32 cj of its ci, so x is consumed in 4KB contiguous bursts per
// batch (sequential 32KB runs overall) and out is written as complete 1KB
// rows. acc for all 32 cj = 64 VGPR/lane. W frags from fragment-linear bf16
// workspace (wconv pre-pass), ci-slice L2-resident (same-ci blocks pinned to
// one XCD). Raw s_barrier (NOT __syncthreads -- that drains vmcnt) + counted
// vmcnt keeps the 2-deep DMA pipeline in flight across barriers.

typedef __bf16 bf16x8 __attribute__((ext_vector_type(8)));  // MFMA A/B operand
typedef float  f32x4  __attribute__((ext_vector_type(4)));  // MFMA C/D

union bfpack { unsigned short s[8]; bf16x8 v; };

__device__ __forceinline__ unsigned short f2bf(float f) {
  union { float f; unsigned u; } v; v.f = f;
  unsigned r = v.u + 0x7fffu + ((v.u >> 16) & 1u);   // RNE (inputs finite)
  return (unsigned short)(r >> 16);
}

typedef __attribute__((address_space(1))) const void GV;
typedef __attribute__((address_space(3))) void LV;

// ---------------- Kernel A: W fp32 -> bf16, fragment-linear ----------------
// Wc (ushort): [n][khp 0..7][nt 0..3][lane 0..63][j 0..7]
//   = W[n][o = nt*16 + (lane&15)][k = khp*32 + (lane>>4)*8 + j]   (R4-proven)
// LDS bounce so global writes are linear 16B/lane (R4 wrote scattered 8B).
__global__ __launch_bounds__(256) void wconv_kernel(
    const float* __restrict__ Wk, unsigned short* __restrict__ Wc) {
  __shared__ unsigned short F[64 * 264];   // [o][k] bf16, +8 pad breaks banks
  const int n = blockIdx.x, t = threadIdx.x;
  const float4* src = (const float4*)(Wk + (size_t)n * 16384);
  #pragma unroll
  for (int it = 0; it < 16; ++it) {
    const int idx = it * 256 + t;          // o = idx>>6, k0 = (idx&63)*4
    float4 g = src[idx];
    const int o = idx >> 6, k0 = (idx & 63) * 4;
    ushort4 p; p.x = f2bf(g.x); p.y = f2bf(g.y); p.z = f2bf(g.z); p.w = f2bf(g.w);
    *(ushort4*)&F[o * 264 + k0] = p;
  }
  __syncthreads();
  unsigned short* dst = Wc + (size_t)n * 16384;
  #pragma unroll
  for (int it = 0; it < 8; ++it) {
    const int g = it * 256 + t;            // 16B granule: [ks][nt][q][o15]
    const int ks = g >> 8, nt = (g >> 6) & 3, q = (g >> 4) & 3, o15 = g & 15;
    *(uint4*)&dst[(size_t)g * 8] =
        *(const uint4*)&F[(nt * 16 + o15) * 264 + ks * 32 + q * 8];
  }
}

// ---------------- Kernel B: main compute ----------------
// 512 blocks = (ci 0..31) x (bsl 0..15); 512 threads = 8 waves.
// Wave w owns chunks cj = w*4..w*4+3, all 16 batches, all 64 o.
// Stage khp = kh-pair: 16 b x 4KB CONTIGUOUS x rows, DMA'd to LDS dbuf.
__global__ __launch_bounds__(512, 2) void comp_kernel(
    const float* __restrict__ x, const unsigned short* __restrict__ Wc,
    const float* __restrict__ bk, float* __restrict__ out) {
  __shared__ __align__(16) char Xs[2][16][4096];   // 128 KB x dbuf
  __shared__ float bs[2048];                       //   8 KB bias (wave-local use)

  const int bid = blockIdx.x;
  // XCD pinning: xcd = bid&7 (round-robin dispatch). ci = xcd*4 + (j>>4) puts
  // all 16 bsl-blocks of a ci on ONE XCD -> its 1MiB Wc slice stays L2-hot.
  const int xcd = bid & 7, j = bid >> 3;
  const int ci  = xcd * 4 + (j >> 4);
  const int bsl = j & 15;
  const int t = threadIdx.x, wave = t >> 6, lane = t & 63;
  const int m15 = lane & 15, quad = lane >> 4;

  // bias slice: 2048 consecutive floats; wave w writes/reads bs[w*256..+255].
  float4 bfrag = *(const float4*)(bk + (size_t)ci * 2048 + t * 4);
  *(float4*)&bs[t * 4] = bfrag;

  const char* xrow = (const char*)x + (size_t)ci * 32768;   // + b*1MiB + khp*4KB

  // DMA stage khp: wave stages batches {2w, 2w+1}, 8 x 1KB instrs, source
  // 16B-granule XOR swizzle within 128B lines (dest linear, G21) so the
  // ds_read_b128 side is a free 2-way bank alias.
  auto stage_issue = [&](int khp) {
    char* db = &Xs[khp & 1][0][0];
    #pragma unroll
    for (int i = 0; i < 8; ++i) {
      const int bl = 2 * wave + (i >> 2);
      const int off = (i & 3) * 1024 + lane * 16;
      const char* src = xrow + (size_t)(bsl * 16 + bl) * 1048576 + khp * 4096
                        + (off ^ ((bl & 7) << 4));
      __builtin_amdgcn_global_load_lds((GV*)src, (LV*)(db + bl * 4096 + off),
                                       16, 0, 0);
    }
  };

  // W fragments: lane-linear 16B loads from the fragment-linear slab.
  const unsigned short* wp = Wc + (size_t)(ci * 32 + wave * 4) * 16384 + lane * 8;
  bf16x8 bwA[4][4], bwB[4][4];
  auto wload = [&](int khp, bf16x8 (*bw)[4]) {
    #pragma unroll
    for (int c = 0; c < 4; ++c)
      #pragma unroll
      for (int nt = 0; nt < 4; ++nt)
        bw[c][nt] = *(const bf16x8*)(wp + (size_t)c * 16384 + khp * 2048 + nt * 512);
  };

  // Prologue: 2-deep pipeline. FIFO: [bias1][D0 8][W0 16][D1 8][W1 16] = 49.
  stage_issue(0); wload(0, bwA);
  stage_issue(1); wload(1, bwB);
  __builtin_amdgcn_sched_barrier(0);

  f32x4 acc[4][4];
  #pragma unroll
  for (int c = 0; c < 4; ++c)
    #pragma unroll
    for (int nt = 0; nt < 4; ++nt) acc[c][nt] = (f32x4){0, 0, 0, 0};

  const int key = (m15 & 7) << 4;

  #pragma unroll
  for (int khp = 0; khp < 8; ++khp) {
    // Counted wait: outstanding = D(khp)8+W(khp)16+D(khp+1)8+W(khp+1)16 = 48
    // (+bias at khp=0). vmcnt(40) -> D(khp) landed, next stage stays in
    // flight. Compiler adds its own counted wait for the W-register uses.
    if (khp < 7) asm volatile("s_waitcnt vmcnt(40)" ::: "memory");
    else         asm volatile("s_waitcnt vmcnt(16)" ::: "memory");
    __builtin_amdgcn_sched_barrier(0);
    __builtin_amdgcn_s_barrier();   // bar1: every wave's stage-khp DMA landed

    bf16x8 (*bw)[4] = (khp & 1) ? bwB : bwA;   // khp compile-time -> static
    const char* Xb = &Xs[khp & 1][m15][0];
    #pragma unroll
    for (int c = 0; c < 4; ++c) {
      const int cj = wave * 4 + c;
      const int r0 = (quad >> 1) * 2048 + cj * 64 + (quad & 1) * 32;
      float4 v0 = *(const float4*)(Xb + ((r0)      ^ key));
      float4 v1 = *(const float4*)(Xb + ((r0 + 16) ^ key));
      bfpack a;
      a.s[0] = f2bf(v0.x); a.s[1] = f2bf(v0.y); a.s[2] = f2bf(v0.z); a.s[3] = f2bf(v0.w);
      a.s[4] = f2bf(v1.x); a.s[5] = f2bf(v1.y); a.s[6] = f2bf(v1.z); a.s[7] = f2bf(v1.w);
      // Swapped operands: A=W (rows=o), B=x (cols=batch) -> D[o][b] (R4-proven).
      #pragma unroll
      for (int nt = 0; nt < 4; ++nt)
        acc[c][nt] = __builtin_amdgcn_mfma_f32_16x16x32_bf16(bw[c][nt], a.v, acc[c][nt], 0, 0, 0);
    }

    // bar2: all waves done READING buf[khp&1] before anyone overwrites it.
    asm volatile("s_waitcnt lgkmcnt(0)" ::: "memory");
    __builtin_amdgcn_sched_barrier(0);
    __builtin_amdgcn_s_barrier();

    if (khp < 6) {
      __builtin_amdgcn_sched_barrier(0);
      stage_issue(khp + 2);                          // into buf[khp&1], now safe
      wload(khp + 2, (khp & 1) ? bwB : bwA);         // regs consumed this iter
      __builtin_amdgcn_sched_barrier(0);
    }
  }

  // Epilogue: D row(o) = nt*16 + quad*4 + r, col(b) = m15. Block covers ALL
  // cj of ci -> complete 1KB out rows, float4 stores.
  const int bg = bsl * 16 + m15;
  float* op = out + (size_t)bg * 65536 + (size_t)(ci * 8) * 256;
  #pragma unroll
  for (int c = 0; c < 4; ++c) {
    const int cj = wave * 4 + c;
    #pragma unroll
    for (int nt = 0; nt < 4; ++nt) {
      const int o0 = nt * 16 + quad * 4;             // o0..o0+3, one oh row
      float4 b4 = *(const float4*)&bs[cj * 64 + o0];
      float4 res;
      res.x = fmaxf(acc[c][nt][0] + b4.x, 0.f);
      res.y = fmaxf(acc[c][nt][1] + b4.y, 0.f);
      res.z = fmaxf(acc[c][nt][2] + b4.z, 0.f);
      res.w = fmaxf(acc[c][nt][3] + b4.w, 0.f);
      *(float4*)&op[(o0 >> 3) * 256 + cj * 8 + (o0 & 7)] = res;
    }
  }
}

extern "C" void kernel_launch(void* const* d_in, const int* in_sizes, int n_in,
                              void* d_out, int out_size, void* d_ws, size_t ws_size,
                              hipStream_t stream) {
  const float* x  = (const float*)d_in[0];
  const float* Wk = (const float*)d_in[1];
  const float* bk = (const float*)d_in[2];
  float* out = (float*)d_out;
  unsigned short* Wc = (unsigned short*)d_ws;       // 32 MiB workspace
  wconv_kernel<<<dim3(1024), dim3(256), 0, stream>>>(Wk, Wc);
  comp_kernel<<<dim3(512), dim3(512), 0, stream>>>(x, Wc, bk, out);
}